// Round 11
// baseline (409.637 us; speedup 1.0000x reference)
//
#include <hip/hip_runtime.h>

typedef unsigned short u16;
typedef __attribute__((ext_vector_type(8))) _Float16 f16x8;
typedef __attribute__((ext_vector_type(2))) __fp16 fp16v2;
typedef __attribute__((ext_vector_type(4))) float f32x4;
typedef __attribute__((ext_vector_type(16))) float f32x16;

#define T_SEQ 2048
#define NH 16
#define DH 64
#define DM 1024
// NEG * log2(e), masks applied in log2 domain (softmax via exp2)
#define NEG2 (-14426.95f)
// 64^-0.25 * sqrt(log2(e)) : folded so S^T comes out pre-scaled for exp2
#define QS2 (0.42466089f)

__device__ __forceinline__ unsigned pk2(float a, float b) {
  union { fp16v2 v; unsigned u; } c;
  c.v = __builtin_amdgcn_cvt_pkrtz(a, b);
  return c.u;
}
__device__ __forceinline__ u16 f2h(float a) {
  union { _Float16 h; u16 u; } c; c.h = (_Float16)a; return c.u;
}

__device__ __forceinline__ void async_load16(const void* g, void* l) {
  __builtin_amdgcn_global_load_lds(
      (const __attribute__((address_space(1))) unsigned int*)(g),
      (__attribute__((address_space(3))) unsigned int*)(l), 16, 0, 0);
}

// ---------------- convert fp32 -> fp16 (WEIGHTS ONLY; X is converted in-GEMM) ----
__global__ __launch_bounds__(256) void convert_w(
    const float* __restrict__ Wq, const float* __restrict__ Wk,
    const float* __restrict__ Wv, const float* __restrict__ Wo,
    u16* __restrict__ wb) {
  int blk = blockIdx.x;
  int s = blk >> 9;
  const float* src = (s == 0) ? Wq : (s == 1) ? Wk : (s == 2) ? Wv : Wo;
  u16* dst = wb + (size_t)s * 1048576u;
  blk &= 511;
  size_t base = (size_t)blk * 2048 + (size_t)threadIdx.x * 8;
  float4 a = *(const float4*)(src + base);
  float4 b2 = *(const float4*)(src + base + 4);
  uint4 st;
  st.x = pk2(a.x, a.y); st.y = pk2(a.z, a.w);
  st.z = pk2(b2.x, b2.y); st.w = pk2(b2.z, b2.w);
  *(uint4*)(dst + base) = st;
}

// ---------------- fused QKV projection GEMM: 256x128, BK=32, fp32-X in-staging cvt ----
// Round-11: X staged from fp32 q/k/v DIRECTLY (convert fused). Per wave per K-tile:
//   4 float4 loads (issued at body(kt) for tile kt+2, T14 issue-early) -> regs,
//   converted (pk2) + ds_write_b128 at body(kt) for tile kt+1 (write-late; the
//   HBM latency hides under one full K-tile). W stays on global_load_lds.
// LDS LAYOUT UNCHANGED (cell = 1KB, dest = base + lane*16), so fragment reads and
// epilogues are byte-identical to round 9/10.
// vmcnt at barrier-top: outstanding = Xld(kt+1)x4 + W(kt+1) [newest 5] + W(kt)
// -> vmcnt(5) drains W(kt) only. Compiler inserts its own waits for the X reg
// loads at the pk2 use point (one K-tile after issue -> arrived).
// ds_write visibility: lgkmcnt(0) before each barrier.
// Buffer safety (tri-buffer): X write(kt+1) -> buf[(kt+1)%3] whose last reader
// (tile kt-2) finished before barrier(kt-1); W gld(kt+2) -> buf[(kt+2)%3] whose
// reader (tile kt-1) finished before barrier(kt).
__global__ __launch_bounds__(512) void gemm_qkv(const float* __restrict__ Xq,
                                                const float* __restrict__ Xk,
                                                const float* __restrict__ Xv,
                                                const u16* __restrict__ Wqb,
                                                const u16* __restrict__ Wkb,
                                                const u16* __restrict__ Wvb,
                                                u16* __restrict__ Qh, u16* __restrict__ Kh,
                                                u16* __restrict__ VTh) {
  __shared__ char lds[73728];  // 3 x 24KB staging; epilogue tile aliases [0, ~68KB)
  const int tid = threadIdx.x;
  const int wid = tid >> 6, lane = tid & 63;
  const int l32 = lane & 31, lh = lane >> 5;
  const int m0 = blockIdx.x * 256;               // t rows
  const int n0 = blockIdx.y * 128;               // ch cols + which
  const int which = n0 >> 10;
  const int n0l = n0 & 1023;
  const float* Xs = (which == 0) ? Xq : (which == 1) ? Xk : Xv;
  const u16* Bw = (which == 0) ? Wqb : (which == 1) ? Wkb : Wvb;
  f32x16 acc[2][2] = {};

  // X: wave w stages cells {2w, 2w+1} = row group w (rows m0+w*32..+31), both
  // 16-col halves. gx0 covers cols 0..15+ (lane slice lh*8), gx1 = gx0+16.
  const float* gx0 = Xs + (size_t)(m0 + wid * 32 + l32) * 1024 + lh * 8;
  const float* gx1 = gx0 + 16;
  const int ldsoX0 = (2 * wid) * 1024;
  const int ldsoX1 = ldsoX0 + 1024;
  // W: wave w stages cell w (row n0l+(w>>1)*32+l32, col half w&1)
  const u16* gw = Bw + (size_t)(n0l + (wid >> 1) * 32 + l32) * 1024 + (wid & 1) * 16 + lh * 8;
  const int ldsoW = 16384 + wid * 1024;

  const int rOff = (which < 2) ? 16384 : 0;   // Q/K: rows = W; V: rows = X
  const int cOff = 16384 - rOff;
  const int rgo = (which < 2) ? ((wid & 1) * 2) : ((wid >> 1) * 2);
  const int cgo = (which < 2) ? ((wid >> 1) * 2) : ((wid & 1) * 2);

  float4 xa0, xa1, xa2, xa3;   // regs A: tiles kt+2 for even kt
  float4 xb0, xb1, xb2, xb3;   // regs B: tiles kt+2 for odd kt
  // prologue: tile0 X -> regsA -> write buf0; tile1 X -> regsB (written body 0);
  // W(0) -> buf0, W(1) -> buf1 via gload_lds.
  xa0 = *(const float4*)(gx0);      xa1 = *(const float4*)(gx0 + 4);
  xa2 = *(const float4*)(gx1);      xa3 = *(const float4*)(gx1 + 4);
  async_load16(gw, lds + 0 * 24576 + ldsoW);
  xb0 = *(const float4*)(gx0 + 32); xb1 = *(const float4*)(gx0 + 36);
  xb2 = *(const float4*)(gx1 + 32); xb3 = *(const float4*)(gx1 + 36);
  async_load16(gw + 32, lds + 1 * 24576 + ldsoW);
  {
    uint4 p0, p1;
    p0.x = pk2(xa0.x, xa0.y); p0.y = pk2(xa0.z, xa0.w);
    p0.z = pk2(xa1.x, xa1.y); p0.w = pk2(xa1.z, xa1.w);
    p1.x = pk2(xa2.x, xa2.y); p1.y = pk2(xa2.z, xa2.w);
    p1.z = pk2(xa3.x, xa3.y); p1.w = pk2(xa3.z, xa3.w);
    *(uint4*)(lds + ldsoX0 + lane * 16) = p0;
    *(uint4*)(lds + ldsoX1 + lane * 16) = p1;
  }
  asm volatile("s_waitcnt lgkmcnt(0)" ::: "memory");

// body(kt): RL* receive Xld(kt+2); RW* (loaded one body earlier) written as X(kt+1)
#define QKV_BODY(KT, RL0, RL1, RL2, RL3, RW0, RW1, RW2, RW3)                     \
  {                                                                              \
    const int kt = (KT);                                                         \
    if (kt < 31) asm volatile("s_waitcnt vmcnt(5)" ::: "memory");                \
    else         asm volatile("s_waitcnt vmcnt(0)" ::: "memory");                \
    __builtin_amdgcn_s_barrier();                                                \
    asm volatile("" ::: "memory");                                               \
    char* bufc = lds + (kt % 3) * 24576;                                         \
    if (kt < 30) {                                                               \
      char* bufn = lds + ((kt + 2) % 3) * 24576;                                 \
      RL0 = *(const float4*)(gx0 + (kt + 2) * 32);                               \
      RL1 = *(const float4*)(gx0 + (kt + 2) * 32 + 4);                           \
      RL2 = *(const float4*)(gx1 + (kt + 2) * 32);                               \
      RL3 = *(const float4*)(gx1 + (kt + 2) * 32 + 4);                           \
      async_load16(gw + (kt + 2) * 32, bufn + ldsoW);                            \
    }                                                                            \
    const char* rb = bufc + rOff;                                                \
    const char* cb = bufc + cOff;                                                \
    f16x8 r0[2], c0[2], r1[2], c1[2];                                            \
    for (int i = 0; i < 2; ++i) {                                                \
      r0[i] = *(const f16x8*)(rb + ((rgo + i) * 2 + 0) * 1024 + lane * 16);      \
      c0[i] = *(const f16x8*)(cb + ((cgo + i) * 2 + 0) * 1024 + lane * 16);      \
    }                                                                            \
    for (int i = 0; i < 2; ++i) {                                                \
      r1[i] = *(const f16x8*)(rb + ((rgo + i) * 2 + 1) * 1024 + lane * 16);      \
      c1[i] = *(const f16x8*)(cb + ((cgo + i) * 2 + 1) * 1024 + lane * 16);      \
    }                                                                            \
    __builtin_amdgcn_s_setprio(1);                                               \
    for (int i = 0; i < 2; ++i)                                                  \
      for (int j = 0; j < 2; ++j)                                                \
        acc[i][j] = __builtin_amdgcn_mfma_f32_32x32x16_f16(r0[i], c0[j], acc[i][j], 0, 0, 0); \
    for (int i = 0; i < 2; ++i)                                                  \
      for (int j = 0; j < 2; ++j)                                                \
        acc[i][j] = __builtin_amdgcn_mfma_f32_32x32x16_f16(r1[i], c1[j], acc[i][j], 0, 0, 0); \
    __builtin_amdgcn_s_setprio(0);                                               \
    if (kt < 31) {                                                               \
      char* bufw = lds + ((kt + 1) % 3) * 24576;                                 \
      uint4 p0, p1;                                                              \
      p0.x = pk2(RW0.x, RW0.y); p0.y = pk2(RW0.z, RW0.w);                        \
      p0.z = pk2(RW1.x, RW1.y); p0.w = pk2(RW1.z, RW1.w);                        \
      p1.x = pk2(RW2.x, RW2.y); p1.y = pk2(RW2.z, RW2.w);                        \
      p1.z = pk2(RW3.x, RW3.y); p1.w = pk2(RW3.z, RW3.w);                        \
      *(uint4*)(bufw + ldsoX0 + lane * 16) = p0;                                 \
      *(uint4*)(bufw + ldsoX1 + lane * 16) = p1;                                 \
    }                                                                            \
    asm volatile("s_waitcnt lgkmcnt(0)" ::: "memory");                           \
  }

  for (int kt2 = 0; kt2 < 32; kt2 += 2) {
    QKV_BODY(kt2,     xa0, xa1, xa2, xa3, xb0, xb1, xb2, xb3);  // even: load A, write B
    QKV_BODY(kt2 + 1, xb0, xb1, xb2, xb3, xa0, xa1, xa2, xa3);  // odd:  load B, write A
  }
#undef QKV_BODY

  // epilogue. C/D 32x32: col = l32, row = (reg&3)+8*(reg>>2)+4*lh. (unchanged)
  const float s = (which < 2) ? QS2 : 1.0f;
  const int b = m0 >> 11, t0 = m0 & 2047, h0 = n0l >> 6;
  __syncthreads();  // full drain before aliasing staging LDS
  if (which < 2) {
#pragma unroll
    for (int i = 0; i < 2; ++i)
#pragma unroll
      for (int j = 0; j < 2; ++j) {
        int colb = (wid >> 1) * 64 + j * 32 + l32;   // t_local
        int rowb = (wid & 1) * 64 + i * 32 + 4 * lh; // ch base
#pragma unroll
        for (int g = 0; g < 4; ++g) {
          uint2 pv;
          pv.x = pk2(acc[i][j][4 * g + 0] * s, acc[i][j][4 * g + 1] * s);
          pv.y = pk2(acc[i][j][4 * g + 2] * s, acc[i][j][4 * g + 3] * s);
          *(uint2*)(lds + colb * 264 + (rowb + 8 * g) * 2) = pv;
        }
      }
    __syncthreads();
    u16* O = which ? Kh : Qh;
#pragma unroll
    for (int p = 0; p < 8; ++p) {
      int row = p * 32 + (tid >> 4);  // t_local 0..255
      int seg = tid & 15;
      uint4 val = *(const uint4*)(lds + row * 264 + seg * 16);
      int hl = seg >> 3, dh0 = (seg & 7) * 8;
      *(uint4*)(O + (((size_t)(b * NH + h0 + hl) * T_SEQ + t0 + row) << 6) + dh0) = val;
    }
  } else {
#pragma unroll
    for (int i = 0; i < 2; ++i)
#pragma unroll
      for (int j = 0; j < 2; ++j) {
        int colb = (wid & 1) * 64 + j * 32 + l32;    // ch_local
        int rowb = (wid >> 1) * 64 + i * 32 + 4 * lh; // t base
#pragma unroll
        for (int g = 0; g < 4; ++g) {
          uint2 pv;
          pv.x = pk2(acc[i][j][4 * g + 0], acc[i][j][4 * g + 1]);
          pv.y = pk2(acc[i][j][4 * g + 2], acc[i][j][4 * g + 3]);
          *(uint2*)(lds + colb * 520 + (rowb + 8 * g) * 2) = pv;
        }
      }
    __syncthreads();
#pragma unroll
    for (int p = 0; p < 8; ++p) {
      int row = p * 16 + (tid >> 5);  // ch_local 0..127
      int seg = tid & 31;
      uint4 val = *(const uint4*)(lds + row * 520 + seg * 16);
      int h = h0 + (row >> 6), dh = row & 63;
      *(uint4*)(VTh + (((size_t)(b * NH + h) * DH + dh) << 11) + t0 + seg * 8) = val;
    }
  }
}

// ---------------- output projection GEMM: 256x128/BK=32 single-barrier template ----
// (unchanged from round 9/10 -- passing; A input is f16 ctx, no conversion needed)
__global__ __launch_bounds__(512) void gemm_out(const u16* __restrict__ A,
                                                const u16* __restrict__ Bw,
                                                float* __restrict__ O) {
  __shared__ char lds[73728];
  const int tid = threadIdx.x;
  const int wid = tid >> 6, lane = tid & 63;
  const int l32 = lane & 31, lh = lane >> 5;
  const int m0 = blockIdx.x * 256, n0 = blockIdx.y * 128;
  f32x16 acc[2][2] = {};

  const u16* gsrc[3]; int ldso[3];
#pragma unroll
  for (int u = 0; u < 3; ++u) {
    int c = wid * 3 + u;
    ldso[u] = c * 1024;
    if (c < 16)
      gsrc[u] = A + (size_t)(m0 + (c >> 1) * 32 + l32) * 1024 + (c & 1) * 16 + lh * 8;
    else {
      int cw = c - 16;
      gsrc[u] = Bw + (size_t)(n0 + (cw >> 1) * 32 + l32) * 1024 + (cw & 1) * 16 + lh * 8;
    }
  }
  const int rgo = (wid >> 1) * 2, cgo = (wid & 1) * 2;

#pragma unroll
  for (int u = 0; u < 3; ++u) async_load16(gsrc[u] + 0 * 32, lds + 0 * 24576 + ldso[u]);
#pragma unroll
  for (int u = 0; u < 3; ++u) async_load16(gsrc[u] + 1 * 32, lds + 1 * 24576 + ldso[u]);

  int slotc = 0, slotn = 2;
  for (int kt = 0; kt < 32; ++kt) {
    if (kt < 31) asm volatile("s_waitcnt vmcnt(3)" ::: "memory");
    else         asm volatile("s_waitcnt vmcnt(0)" ::: "memory");
    __builtin_amdgcn_s_barrier();
    asm volatile("" ::: "memory");
    char* bufc = lds + slotc * 24576;
    if (kt < 30) {
      char* bufn = lds + slotn * 24576;
      int ko = (kt + 2) * 32;
#pragma unroll
      for (int u = 0; u < 3; ++u) async_load16(gsrc[u] + ko, bufn + ldso[u]);
    }
    const char* rb = bufc;           // X region (rows = t)
    const char* cb = bufc + 16384;   // W region (rows = e)
    f16x8 r0[2], c0[2], r1[2], c1[2];
#pragma unroll
    for (int i = 0; i < 2; ++i) {
      r0[i] = *(const f16x8*)(rb + ((rgo + i) * 2 + 0) * 1024 + lane * 16);
      c0[i] = *(const f16x8*)(cb + ((cgo + i) * 2 + 0) * 1024 + lane * 16);
    }
#pragma unroll
    for (int i = 0; i < 2; ++i) {
      r1[i] = *(const f16x8*)(rb + ((rgo + i) * 2 + 1) * 1024 + lane * 16);
      c1[i] = *(const f16x8*)(cb + ((cgo + i) * 2 + 1) * 1024 + lane * 16);
    }
    __builtin_amdgcn_s_setprio(1);
#pragma unroll
    for (int i = 0; i < 2; ++i)
#pragma unroll
      for (int j = 0; j < 2; ++j)
        acc[i][j] = __builtin_amdgcn_mfma_f32_32x32x16_f16(r0[i], c0[j], acc[i][j], 0, 0, 0);
#pragma unroll
    for (int i = 0; i < 2; ++i)
#pragma unroll
      for (int j = 0; j < 2; ++j)
        acc[i][j] = __builtin_amdgcn_mfma_f32_32x32x16_f16(r1[i], c1[j], acc[i][j], 0, 0, 0);
    __builtin_amdgcn_s_setprio(0);
    slotc = (slotc == 2) ? 0 : slotc + 1;
    slotn = (slotn == 2) ? 0 : slotn + 1;
  }
  // epilogue: direct fp32 stores. row = rowb + 8*g + rr, col contiguous over l32.
#pragma unroll
  for (int i = 0; i < 2; ++i)
#pragma unroll
    for (int j = 0; j < 2; ++j) {
      int col = n0 + (wid & 1) * 64 + j * 32 + l32;
      int rowb = m0 + (wid >> 1) * 64 + i * 32 + 4 * lh;
#pragma unroll
      for (int g = 0; g < 4; ++g)
#pragma unroll
        for (int rr = 0; rr < 4; ++rr)
          O[(size_t)(rowb + 8 * g + rr) * 1024 + col] = acc[i][j][4 * g + rr];
    }
}

// ---------------- Flash attention (S^T formulation, fp16, 8 waves) ----------------
// (unchanged from round 10 -- passing: 1 q-tile/block, grid 1024, 4 blocks/CU,
//  single-buffered V, halved pls, MFMA row-sum, defer-max)
__global__ __launch_bounds__(512) void attn_kernel(const u16* __restrict__ Qh,
                                                   const u16* __restrict__ Kh,
                                                   const u16* __restrict__ VTh,
                                                   const float* __restrict__ attn_mask,
                                                   const int* __restrict__ mfp,
                                                   u16* __restrict__ ctx) {
  __shared__ char kls[2][8192];   // K chunk (64s x 64k), cells (st*2+kk), x2 dbuf
  __shared__ char vls[8192];      // V^T chunk (64dh x 64s), cells (nt*2+kk), single
  __shared__ char pls[8][1024];   // per-wave P (16q x 32s) in A-frag order, kk-phased
  __shared__ int mzf;             // 1 if any pad-mask zero for this b

  const int tid = threadIdx.x;
  const int wid = tid >> 6, lane = tid & 63;
  const int lm = lane & 15, lq = lane >> 4;
  const int bid = blockIdx.x;
  const int bh_i = bid & 63;
  const int qt = 15 - (bid >> 6);         // descending work order
  const int b = bh_i >> 4, h = bh_i & 15;
  const int mf = *mfp;
  const size_t bh = (size_t)(b * NH + h);
  const u16* Qbh = Qh + bh * T_SEQ * DH;
  const u16* Kbh = Kh + bh * T_SEQ * DH;
  const u16* VTbh = VTh + bh * DH * T_SEQ;
  const float* amb = attn_mask + (size_t)b * T_SEQ;

  f16x8 onev;
#pragma unroll
  for (int i = 0; i < 8; ++i) onev[i] = (_Float16)1.0f;

  if (tid == 0) mzf = 0;
  __syncthreads();
  {
    int az = 0;
    for (int i = tid; i < T_SEQ; i += 512) az |= (amb[i] == 0.0f);
    if (az) mzf = 1;  // benign same-value race
  }
  __syncthreads();
  const int maskzero = mzf;

  const int qw = qt * 128 + wid * 16;
  f16x8 qf[2];
  qf[0] = *(const f16x8*)(Qbh + (size_t)(qw + lm) * DH + lq * 8);
  qf[1] = *(const f16x8*)(Qbh + (size_t)(qw + lm) * DH + 32 + lq * 8);

  f32x4 acc[4] = {};
  f32x4 accs = {};                 // row-sum accumulator: accs[r] = lsum(q=lq*4+r)
  float mprev = -1e30f;

  const int nch = mf ? (qt + 1) * 2 : 32;
  // prologue: issue K(0) only (V is loaded per-chunk)
  async_load16(Kbh + (size_t)((wid >> 1) * 16 + lm) * DH + (wid & 1) * 32 + lq * 8,
               kls[0] + wid * 1024);

  for (int c = 0; c < nch; ++c) {
    const int s0 = c * 64;
    asm volatile("s_waitcnt vmcnt(0)" ::: "memory");  // K(c) landed (sole outstanding)
    __builtin_amdgcn_s_barrier();   // all waves' K(c) landed; vls free (PV(c-1) done)
    asm volatile("" ::: "memory");
    // V(c) first (older in vmcnt order), then K(c+1)
    async_load16(VTbh + (size_t)((wid >> 1) * 16 + lm) * T_SEQ + s0 + (wid & 1) * 32 + lq * 8,
                 vls + wid * 1024);
    if (c + 1 < nch) {
      async_load16(Kbh + (size_t)(s0 + 64 + (wid >> 1) * 16 + lm) * DH + (wid & 1) * 32 + lq * 8,
                   kls[(c + 1) & 1] + wid * 1024);
    }
    const char* kcur = kls[c & 1];

    f32x4 sc[4];
    for (int st = 0; st < 4; ++st) {
      f32x4 z = {0.f, 0.f, 0.f, 0.f};
      sc[st] = z;
      for (int kk = 0; kk < 2; ++kk) {
        f16x8 kf = *(const f16x8*)(kcur + ((st * 2 + kk) * 64 + lane) * 16);
        sc[st] = __builtin_amdgcn_mfma_f32_16x16x32_f16(kf, qf[kk], sc[st], 0, 0, 0);
      }
    }
    if (maskzero) {  // rare path: pad bias straight from global (L2-resident)
      for (int st = 0; st < 4; ++st) {
        f32x4 mb = *(const f32x4*)(amb + s0 + st * 16 + lq * 4);
        for (int r = 0; r < 4; ++r)
          if (mb[r] == 0.0f) sc[st][r] += NEG2;
      }
    }
    if (mf && (s0 + 64 > qw)) {
      int qg = qw + lm;
      for (int st = 0; st < 4; ++st)
        for (int r = 0; r < 4; ++r)
          if (s0 + st * 16 + lq * 4 + r > qg) sc[st][r] = NEG2;
    }
    // chunk max via max3-shaped tree (8 ops)
    float u0 = fmaxf(fmaxf(sc[0][0], sc[0][1]), sc[0][2]);
    float u1 = fmaxf(fmaxf(sc[0][3], sc[1][0]), sc[1][1]);
    float u2 = fmaxf(fmaxf(sc[1][2], sc[1][3]), sc[2][0]);
    float u3 = fmaxf(fmaxf(sc[2][1], sc[2][2]), sc[2][3]);
    float u4 = fmaxf(fmaxf(sc[3][0], sc[3][1]), sc[3][2]);
    float mx = fmaxf(fmaxf(fmaxf(u0, u1), u2), fmaxf(fmaxf(u3, u4), sc[3][3]));
    mx = fmaxf(mx, __shfl_xor(mx, 16));
    mx = fmaxf(mx, __shfl_xor(mx, 32));
    // defer-max: rescale only when the max grew by more than THR=8 (log2 domain)
    if (__ballot(mx > mprev + 8.0f) != 0ull) {
      float mn2 = fmaxf(mprev, mx);
      float alpha = exp2f(mprev - mn2);
      for (int r = 0; r < 4; ++r) {
        float ar = __shfl(alpha, lq * 4 + r);
        for (int nt = 0; nt < 4; ++nt) acc[nt][r] *= ar;
        accs[r] *= ar;
      }
      mprev = mn2;
    }
    for (int st = 0; st < 4; ++st)
      for (int r = 0; r < 4; ++r)
        sc[st][r] = exp2f(sc[st][r] - mprev);

    // ---- kk=0: P write (st 0,1) -> PV kk0 ----
    {
      char* pw = pls[wid];
      for (int st = 0; st < 2; ++st) {
        int lqp = (st & 1) * 2 + (lq >> 1);
        uint2 pv;
        pv.x = pk2(sc[st][0], sc[st][1]);
        pv.y = pk2(sc[st][2], sc[st][3]);
        *(uint2*)(pw + (lqp * 16 + lm) * 16 + (lq & 1) * 8) = pv;
      }
    }
    // V(c) landed; K(c+1) (newest) may stay in flight
    if (c + 1 < nch) asm volatile("s_waitcnt vmcnt(1)" ::: "memory");
    else             asm volatile("s_waitcnt vmcnt(0)" ::: "memory");
    asm volatile("s_waitcnt lgkmcnt(0)" ::: "memory");
    {
      f16x8 pf = *(const f16x8*)(pls[wid] + lane * 16);
      for (int nt = 0; nt < 4; ++nt) {
        f16x8 vf = *(const f16x8*)(vls + ((nt * 2 + 0) * 64 + lane) * 16);
        acc[nt] = __builtin_amdgcn_mfma_f32_16x16x32_f16(pf, vf, acc[nt], 0, 0, 0);
      }
      accs = __builtin_amdgcn_mfma_f32_16x16x32_f16(pf, onev, accs, 0, 0, 0);
    }
    // ---- kk=1: P write (st 2,3) -> PV kk1 (same pls cell; same-wave DS order) ----
    {
      char* pw = pls[wid];
      for (int st = 2; st < 4; ++st) {
        int lqp = (st & 1) * 2 + (lq >> 1);
        uint2 pv;
        pv.x = pk2(sc[st][0], sc[st][1]);
        pv.y = pk2(sc[st][2], sc[st][3]);
        *(uint2*)(pw + (lqp * 16 + lm) * 16 + (lq & 1) * 8) = pv;
      }
    }
    asm volatile("s_waitcnt lgkmcnt(0)" ::: "memory");
    {
      f16x8 pf = *(const f16x8*)(pls[wid] + lane * 16);
      for (int nt = 0; nt < 4; ++nt) {
        f16x8 vf = *(const f16x8*)(vls + ((nt * 2 + 1) * 64 + lane) * 16);
        acc[nt] = __builtin_amdgcn_mfma_f32_16x16x32_f16(pf, vf, acc[nt], 0, 0, 0);
      }
      accs = __builtin_amdgcn_mfma_f32_16x16x32_f16(pf, onev, accs, 0, 0, 0);
    }
  }
  // epilogue: accs[r] holds lsum for q=qw+lq*4+r (same row layout as acc)
  for (int r = 0; r < 4; ++r) {
    float ir = 1.0f / accs[r];
    int t = qw + lq * 4 + r;
    for (int nt = 0; nt < 4; ++nt)
      ctx[((size_t)(b * T_SEQ + t) * DM) + h * DH + nt * 16 + lm] = f2h(acc[nt][r] * ir);
  }
}

extern "C" void kernel_launch(void* const* d_in, const int* in_sizes, int n_in,
                              void* d_out, int out_size, void* d_ws, size_t ws_size,
                              hipStream_t stream) {
  const float* q = (const float*)d_in[0];
  const float* k = (const float*)d_in[1];
  const float* v = (const float*)d_in[2];
  const float* attn_mask = (const float*)d_in[3];
  const float* Wq = (const float*)d_in[4];
  const float* Wk = (const float*)d_in[5];
  const float* Wv = (const float*)d_in[6];
  const float* Wo = (const float*)d_in[7];
  const int* mf = (const int*)d_in[8];

  u16* ws = (u16*)d_ws;
  u16* wqb = ws + 3u * 8388608u;      // f16 weights x4 (layout kept from prior rounds)
  u16* wkb = wqb + 1048576u;
  u16* wvb = wkb + 1048576u;
  u16* wob = wvb + 1048576u;
  u16* Qh  = wob + 1048576u;          // [bh][t][64]
  u16* Kh  = Qh + 8388608u;           // [bh][t][64]
  u16* VTh = Kh + 8388608u;           // [bh][dh][2048]
  u16* ctxb = ws;                     // ctx f16 [b][t][1024] (region formerly qb)

  convert_w<<<2048, 256, 0, stream>>>(Wq, Wk, Wv, Wo, wqb);

  dim3 gq(32, 24);
  gemm_qkv<<<gq, 512, 0, stream>>>(q, k, v, wqb, wkb, wvb, Qh, Kh, VTh);

  attn_kernel<<<1024, 512, 0, stream>>>(Qh, Kh, VTh, attn_mask, mf, ctxb);

  dim3 gg(32, 8);
  gemm_out<<<gg, 512, 0, stream>>>(ctxb, wob, (float*)d_out);
}